// Round 3
// baseline (1945.188 us; speedup 1.0000x reference)
//
#include <hip/hip_runtime.h>
#include <math.h>

typedef unsigned short u16;                                   // bf16 bit pattern
typedef __attribute__((ext_vector_type(8))) short bf16x8;     // MFMA A/B frag
typedef __attribute__((ext_vector_type(4))) float f32x4;      // MFMA C/D frag

__device__ __forceinline__ float b2f(u16 u) {
    union { unsigned int i; float f; } v; v.i = ((unsigned int)u) << 16; return v.f;
}
__device__ __forceinline__ u16 f2b(float f) {
    union { float f; unsigned int u; } v; v.f = f;
    unsigned int r = 0x7FFFu + ((v.u >> 16) & 1u);
    return (u16)((v.u + r) >> 16);   // RNE
}

// ---------- dtype detector: bf16 data never has exp>=140; f32 mantissa halves do ----------
__global__ void detect_dtype(const u16* __restrict__ x, int* __restrict__ flag) {
    __shared__ int cnt;
    if (threadIdx.x == 0) cnt = 0;
    __syncthreads();
    int c = 0;
    for (int i = threadIdx.x; i < 4096; i += 256) {
        int e = (x[i] >> 7) & 0xFF;
        if (e >= 140 && e != 255) c++;
    }
    atomicAdd(&cnt, c);
    __syncthreads();
    if (threadIdx.x == 0) *flag = (cnt > 64) ? 1 : 0;
}

// ---------- generic cast-to-bf16 (or copy) ----------
__global__ void cast_bf16(const void* __restrict__ src, u16* __restrict__ dst, int n,
                          const int* __restrict__ flagp) {
    int i = blockIdx.x * 256 + threadIdx.x;
    if (i >= n) return;
    dst[i] = (*flagp) ? f2b(((const float*)src)[i]) : ((const u16*)src)[i];
}

// ---------- generic transpose with offsets, dynamic in/out dtype ----------
// reads  in[ioff + z*ibstride + r*Cfull + c0 + c]   (r in [0,R), c in [0, gridDim.x*32))
// writes out[ooff + z*obstride + c*ostride + r]
__global__ __launch_bounds__(256) void transpose_g(const void* __restrict__ in,
                                                   void* __restrict__ out,
                                                   int R, int Cfull, int c0, int ostride,
                                                   long ioff, long ibstride,
                                                   long ooff, long obstride,
                                                   const int* __restrict__ flagp,
                                                   int in_dyn, int out_dyn) {
    __shared__ u16 t[32][33];
    const int f = *flagp;
    const int in_f32 = in_dyn & f, out_f32 = out_dyn & f;
    const long ib = ioff + (long)blockIdx.z * ibstride;
    const long ob = ooff + (long)blockIdx.z * obstride;
    int cl0 = blockIdx.x * 32, r0 = blockIdx.y * 32;
    int tx = threadIdx.x, ty = threadIdx.y;   // block (32,8)
    const float* inf = (const float*)in;
    const u16* inh = (const u16*)in;
#pragma unroll
    for (int i = 0; i < 4; i++) {
        long src = ib + (long)(r0 + ty + i * 8) * Cfull + c0 + cl0 + tx;
        t[ty + i * 8][tx] = in_f32 ? f2b(inf[src]) : inh[src];
    }
    __syncthreads();
#pragma unroll
    for (int i = 0; i < 4; i++) {
        long dst = ob + (long)(cl0 + ty + i * 8) * ostride + r0 + tx;
        u16 v = t[tx][ty + i * 8];
        if (out_f32) ((float*)out)[dst] = b2f(v);
        else         ((u16*)out)[dst] = v;
    }
}

// ---------- repack up_w [c(512)][o(256)][kh][kw] -> WU [(khw*256+o)][c] ----------
__global__ void repack_w(const void* __restrict__ uw, u16* __restrict__ wu,
                         const int* __restrict__ flagp) {
    int o_ = blockIdx.x * 256 + threadIdx.x;      // 524288 total
    int ccol = o_ & 511, nrow = o_ >> 9;
    int o = nrow & 255, khw = nrow >> 8;
    int src = ccol * 1024 + o * 4 + khw;
    wu[o_] = (*flagp) ? f2b(((const float*)uw)[src]) : ((const u16*)uw)[src];
}

// ---------- GEMM: C[M,N] = epi(A[M,K] @ W[N,K]^T + bias + R); bf16 in/out, fp32 acc
__global__ __launch_bounds__(256) void gemm_bf16(const u16* __restrict__ A,
                                                 const u16* __restrict__ W,
                                                 const u16* __restrict__ bias,
                                                 const u16* __restrict__ Rres,
                                                 u16* __restrict__ C,
                                                 int M, int N, int K, int gelu) {
    __shared__ u16 As[128][40];
    __shared__ u16 Bs[128][40];
    const int tid = threadIdx.x;
    const int m0 = blockIdx.y * 128, n0 = blockIdx.x * 128;
    const int wave = tid >> 6, lane = tid & 63;
    const int wm = (wave >> 1) * 64, wn = (wave & 1) * 64;
    const int quad = lane >> 4, l16 = lane & 15;
    const int rA = tid >> 2, kp = (tid & 3) * 8;

    f32x4 acc[4][4];
#pragma unroll
    for (int i = 0; i < 4; i++)
#pragma unroll
        for (int j = 0; j < 4; j++)
#pragma unroll
            for (int r = 0; r < 4; r++) acc[i][j][r] = 0.f;

    for (int kt = 0; kt < K; kt += 32) {
#pragma unroll
        for (int r = 0; r < 2; r++) {
            int row = rA + r * 64;
            *(uint4*)&As[row][kp] = *(const uint4*)&A[(size_t)(m0 + row) * K + kt + kp];
            *(uint4*)&Bs[row][kp] = *(const uint4*)&W[(size_t)(n0 + row) * K + kt + kp];
        }
        __syncthreads();
        bf16x8 af[4], bfr[4];
#pragma unroll
        for (int i = 0; i < 4; i++) {
            af[i]  = *(const bf16x8*)&As[wm + i * 16 + l16][quad * 8];
            bfr[i] = *(const bf16x8*)&Bs[wn + i * 16 + l16][quad * 8];
        }
#pragma unroll
        for (int i = 0; i < 4; i++)
#pragma unroll
            for (int j = 0; j < 4; j++)
                acc[i][j] = __builtin_amdgcn_mfma_f32_16x16x32_bf16(af[i], bfr[j], acc[i][j], 0, 0, 0);
        __syncthreads();
    }

#pragma unroll
    for (int i = 0; i < 4; i++)
#pragma unroll
        for (int j = 0; j < 4; j++) {
            int col = n0 + wn + j * 16 + l16;
            float bv = bias ? b2f(bias[col]) : 0.f;
#pragma unroll
            for (int r = 0; r < 4; r++) {
                int rowg = m0 + wm + i * 16 + quad * 4 + r;
                float v = acc[i][j][r] + bv;
                if (Rres) v += b2f(Rres[(size_t)rowg * N + col]);
                if (gelu) v = 0.5f * v * (1.f + erff(v * 0.70710678118654752f));
                C[(size_t)rowg * N + col] = f2b(v);
            }
        }
}

// ---------- convT epilogue: scatter TMPC[m=(pix)][n=(khw,o)] -> SC[tok,o] + bias ----------
__global__ void conv_epilogue(const u16* __restrict__ t, const u16* __restrict__ ub,
                              u16* __restrict__ sc) {
    int idx = blockIdx.x * 256 + threadIdx.x;     // T*256 total
    int c = idx & 255, rest = idx >> 8;
    int Ww = rest & 127, Hl = rest >> 7;          // Hl in [0, T/128)
    int m = (Hl >> 1) * 64 + (Ww >> 1);
    int n = (((Hl & 1) * 2 + (Ww & 1)) << 8) + c;
    sc[idx] = f2b(b2f(t[(size_t)m * 1024 + n]) + b2f(ub[c]));
}

// ---------- layernorm over C=256, optional window-partition remap ----------
__global__ __launch_bounds__(256) void ln_kernel(const u16* __restrict__ in,
                                                 const u16* __restrict__ g,
                                                 const u16* __restrict__ bta,
                                                 u16* __restrict__ out, int remap) {
    int wave = threadIdx.x >> 6, lane = threadIdx.x & 63;
    int row = blockIdx.x * 4 + wave;
    const u16* ip = in + (size_t)row * 256 + lane * 4;
    ushort4 u = *(const ushort4*)ip;
    float x0 = b2f(u.x), x1 = b2f(u.y), x2 = b2f(u.z), x3 = b2f(u.w);
    float s1 = x0 + x1 + x2 + x3;
    float s2 = x0 * x0 + x1 * x1 + x2 * x2 + x3 * x3;
#pragma unroll
    for (int o = 32; o > 0; o >>= 1) { s1 += __shfl_xor(s1, o); s2 += __shfl_xor(s2, o); }
    float mu = s1 * (1.f / 256.f);
    float var = s2 * (1.f / 256.f) - mu * mu;
    float rstd = rsqrtf(var + 1e-6f);
    int orow = row;
    if (remap) {
        int Hl = row >> 7, Ww = row & 127;
        orow = ((Hl >> 3) * 16 + (Ww >> 3)) * 64 + (Hl & 7) * 8 + (Ww & 7);
    }
    ushort4 gv = *(const ushort4*)(g + lane * 4);
    ushort4 bv = *(const ushort4*)(bta + lane * 4);
    ushort4 o;
    o.x = f2b((x0 - mu) * rstd * b2f(gv.x) + b2f(bv.x));
    o.y = f2b((x1 - mu) * rstd * b2f(gv.y) + b2f(bv.y));
    o.z = f2b((x2 - mu) * rstd * b2f(gv.z) + b2f(bv.z));
    o.w = f2b((x3 - mu) * rstd * b2f(gv.w) + b2f(bv.w));
    *(ushort4*)(out + (size_t)orow * 256 + lane * 4) = o;
}

// ---------- attention: one wave per (window, head) ----------
__global__ __launch_bounds__(64) void attn_kernel(const u16* __restrict__ qkv,
                                                  const u16* __restrict__ tbl,
                                                  u16* __restrict__ out) {
    __shared__ float kS[64][33];
    __shared__ float vS[64][33];
    int wh = blockIdx.x;
    int w = wh >> 3, h = wh & 7;
    int n = threadIdx.x;
    const size_t rb = (size_t)(w * 64 + n) * 768 + h * 32;
    float q[32];
#pragma unroll
    for (int d = 0; d < 32; d++) q[d] = b2f(qkv[rb + d]) * 0.17677669529663687f;
#pragma unroll
    for (int d = 0; d < 32; d++) kS[n][d] = b2f(qkv[rb + 256 + d]);
#pragma unroll
    for (int d = 0; d < 32; d++) vS[n][d] = b2f(qkv[rb + 512 + d]);
    __syncthreads();
    float s[64];
    int yi = n >> 3, xi = n & 7;
    float mx = -1e30f;
#pragma unroll
    for (int j = 0; j < 64; j++) {
        float a = 0.f;
#pragma unroll
        for (int d = 0; d < 32; d++) a += q[d] * kS[j][d];
        int dy = yi - (j >> 3) + 7, dx = xi - (j & 7) + 7;
        a += b2f(tbl[(dy * 15 + dx) * 8 + h]);
        s[j] = a;
        mx = fmaxf(mx, a);
    }
    float sum = 0.f;
#pragma unroll
    for (int j = 0; j < 64; j++) { s[j] = expf(s[j] - mx); sum += s[j]; }
    float inv = 1.f / sum;
    size_t ob = (size_t)(w * 64 + n) * 256 + h * 32;
#pragma unroll
    for (int d = 0; d < 32; d++) {
        float o = 0.f;
#pragma unroll
        for (int j = 0; j < 64; j++) o += s[j] * vS[j][d];
        out[ob + d] = f2b(o * inv);
    }
}

// ---------- window reverse + shortcut add ----------
__global__ void rev_add(const u16* __restrict__ sc, const u16* __restrict__ t2,
                        u16* __restrict__ xr) {
    int idx = blockIdx.x * 256 + threadIdx.x;
    int c = idx & 255, rest = idx >> 8;
    int Ww = rest & 127, Hl = rest >> 7;
    int wr = ((Hl >> 3) * 16 + (Ww >> 3)) * 64 + (Hl & 7) * 8 + (Ww & 7);
    xr[idx] = f2b(b2f(sc[idx]) + b2f(t2[(size_t)wr * 256 + c]));
}

// =====================================================================
extern "C" void kernel_launch(void* const* d_in, const int* in_sizes, int n_in,
                              void* d_out, int out_size, void* d_ws, size_t ws_size,
                              hipStream_t stream) {
    const void* x      = d_in[0];   // [8,512,64,64]
    const void* skip   = d_in[1];   // [8,256,128,128]
    const void* up_w   = d_in[2];

    u16* ws = (u16*)d_ws;
    int* flag = (int*)ws;                       // ws[0..32)
    u16* WU  = ws + 32;                          // 524288
    size_t off = 32 + 524288;
    u16* SW  = ws + off; off += 65536;
    u16* QW  = ws + off; off += 196608;
    u16* PW  = ws + off; off += 65536;
    u16* W1  = ws + off; off += 262144;
    u16* W2  = ws + off; off += 262144;
    u16* UB  = ws + off; off += 256;
    u16* QB  = ws + off; off += 768;
    u16* PB  = ws + off; off += 256;
    u16* B1  = ws + off; off += 1024;
    u16* B2  = ws + off; off += 256;
    u16* G1  = ws + off; off += 256;
    u16* Bn1 = ws + off; off += 256;
    u16* G2  = ws + off; off += 256;
    u16* Bn2 = ws + off; off += 256;
    u16* TBL = ws + off; off += 1808;
    off = (off + 63) & ~(size_t)63;
    u16* AR = ws + off;

    // pick chunk token count T from available workspace
    long arena = (long)(ws_size / 2) - (long)off;
    int T = 1024;
    const int cand[8] = {131072, 65536, 32768, 16384, 8192, 4096, 2048, 1024};
    for (int i = 0; i < 8; i++)
        if ((long)cand[i] * 2048 <= arena) { T = cand[i]; break; }

    u16* SLA = AR;                    // T*1024 : XT+TMPC -> QKV -> HID
    u16* XT  = SLA;                   // T*128
    u16* TMPC = SLA + (size_t)T * 128;
    u16* SLB = AR + (size_t)T * 1024; // T*256
    u16* SLC = AR + (size_t)T * 1280; // T*256
    u16* SC  = AR + (size_t)T * 1536; // T*256
    u16* XR  = AR + (size_t)T * 1792; // T*256

    // ---- prologue: dtype detect, weight staging ----
    detect_dtype<<<1, 256, 0, stream>>>((const u16*)x, flag);
    cast_bf16<<<256, 256, 0, stream>>>(d_in[4],  SW, 65536, flag);
    cast_bf16<<<768, 256, 0, stream>>>(d_in[9],  QW, 196608, flag);
    cast_bf16<<<256, 256, 0, stream>>>(d_in[11], PW, 65536, flag);
    cast_bf16<<<1024, 256, 0, stream>>>(d_in[14], W1, 262144, flag);
    cast_bf16<<<1024, 256, 0, stream>>>(d_in[16], W2, 262144, flag);
    cast_bf16<<<1, 256, 0, stream>>>(d_in[3],  UB, 256, flag);
    cast_bf16<<<3, 256, 0, stream>>>(d_in[10], QB, 768, flag);
    cast_bf16<<<1, 256, 0, stream>>>(d_in[12], PB, 256, flag);
    cast_bf16<<<4, 256, 0, stream>>>(d_in[15], B1, 1024, flag);
    cast_bf16<<<1, 256, 0, stream>>>(d_in[17], B2, 256, flag);
    cast_bf16<<<1, 256, 0, stream>>>(d_in[5],  G1, 256, flag);
    cast_bf16<<<1, 256, 0, stream>>>(d_in[6],  Bn1, 256, flag);
    cast_bf16<<<1, 256, 0, stream>>>(d_in[7],  G2, 256, flag);
    cast_bf16<<<1, 256, 0, stream>>>(d_in[8],  Bn2, 256, flag);
    cast_bf16<<<8, 256, 0, stream>>>(d_in[13], TBL, 1800, flag);
    repack_w<<<2048, 256, 0, stream>>>(up_w, WU, flag);

    dim3 tb(32, 8);
    const int nb = T / 16384;          // >=1: multi-batch chunks; 0: H-stripes
    const int Hs = T / 128;            // stripe height (when nb==0)
    const int nchunks = (nb >= 1) ? (8 / nb) : (8 * (128 / Hs));

    for (int c = 0; c < nchunks; c++) {
        int b, h0, z;
        if (nb >= 1) { b = c * nb; h0 = 0; z = nb; }
        else { b = c / (128 / Hs); h0 = (c % (128 / Hs)) * Hs; z = 1; }

        // 1) x slice -> XT [T/4, 512]
        transpose_g<<<dim3((nb >= 1) ? 128 : Hs, 16, z), tb, 0, stream>>>(
            x, XT, 512, 4096, (nb >= 1) ? 0 : h0 * 32, 512,
            (long)b * 2097152, 2097152, 0, 2097152, flag, 1, 0);
        // 2) convT GEMM: TMPC[T/4,1024] = XT @ WU^T
        gemm_bf16<<<dim3(8, T / 512), 256, 0, stream>>>(XT, WU, nullptr, nullptr, TMPC,
                                                        T / 4, 1024, 512, 0);
        // 3) scatter + bias -> SC
        conv_epilogue<<<T, 256, 0, stream>>>(TMPC, UB, SC);
        // 4) skip slice -> SKT(SLB) [T, 256]
        transpose_g<<<dim3((nb >= 1) ? 512 : Hs * 4, 8, z), tb, 0, stream>>>(
            skip, SLB, 256, 16384, (nb >= 1) ? 0 : h0 * 128, 256,
            (long)b * 4194304, 4194304, 0, 4194304, flag, 1, 0);
        // 5) Y(SLC) = SKT @ skip_w^T + SC
        gemm_bf16<<<dim3(2, T / 128), 256, 0, stream>>>(SLB, SW, nullptr, SC, SLC, T, 256, 256, 0);
        // 6) LN1 + window partition -> WINS(SLB)
        ln_kernel<<<T / 4, 256, 0, stream>>>(SLC, G1, Bn1, SLB, 1);
        // 7) QKV(SLA) = WINS @ qkv_w^T + qkv_b
        gemm_bf16<<<dim3(6, T / 128), 256, 0, stream>>>(SLB, QW, QB, nullptr, SLA, T, 768, 256, 0);
        // 8) attention -> ATT(SLC)
        attn_kernel<<<T / 8, 64, 0, stream>>>(SLA, TBL, SLC);
        // 9) proj -> TMP2(SLB)
        gemm_bf16<<<dim3(2, T / 128), 256, 0, stream>>>(SLC, PW, PB, nullptr, SLB, T, 256, 256, 0);
        // 10) window reverse + shortcut -> XR
        rev_add<<<T, 256, 0, stream>>>(SC, SLB, XR);
        // 11) LN2 -> N2(SLC)
        ln_kernel<<<T / 4, 256, 0, stream>>>(XR, G2, Bn2, SLC, 0);
        // 12) MLP1: HID(SLA) = gelu(N2 @ w1^T + b1)
        gemm_bf16<<<dim3(8, T / 128), 256, 0, stream>>>(SLC, W1, B1, nullptr, SLA, T, 1024, 256, 1);
        // 13) MLP2: TMP3(SLB) = HID @ w2^T + b2 + XR
        gemm_bf16<<<dim3(2, T / 128), 256, 0, stream>>>(SLA, W2, B2, XR, SLB, T, 256, 1024, 0);
        // 14) TMP3 -> out slice (dtype per flag)
        if (nb >= 1)
            transpose_g<<<dim3(8, 512, z), tb, 0, stream>>>(
                SLB, d_out, 16384, 256, 0, 16384,
                0, 4194304, (long)b * 4194304, 4194304, flag, 0, 1);
        else
            transpose_g<<<dim3(8, T / 32, 1), tb, 0, stream>>>(
                SLB, d_out, T, 256, 0, 16384,
                0, 0, (long)b * 4194304 + h0 * 128, 0, flag, 0, 1);
    }
}

// Round 4
// 1475.806 us; speedup vs baseline: 1.3181x; 1.3181x over previous
//
#include <hip/hip_runtime.h>
#include <math.h>

typedef unsigned short u16;                                   // bf16 bit pattern
typedef __attribute__((ext_vector_type(8))) short bf16x8;     // MFMA A/B frag
typedef __attribute__((ext_vector_type(4))) float f32x4;      // MFMA C/D frag

__device__ __forceinline__ float b2f(u16 u) {
    union { unsigned int i; float f; } v; v.i = ((unsigned int)u) << 16; return v.f;
}
__device__ __forceinline__ u16 f2b(float f) {
    union { float f; unsigned int u; } v; v.f = f;
    unsigned int r = 0x7FFFu + ((v.u >> 16) & 1u);
    return (u16)((v.u + r) >> 16);   // RNE
}

// ---------- dtype detector: bf16 data never has exp>=140; f32 mantissa halves do ----------
__global__ void detect_dtype(const u16* __restrict__ x, int* __restrict__ flag) {
    __shared__ int cnt;
    if (threadIdx.x == 0) cnt = 0;
    __syncthreads();
    int c = 0;
    for (int i = threadIdx.x; i < 4096; i += 256) {
        int e = (x[i] >> 7) & 0xFF;
        if (e >= 140 && e != 255) c++;
    }
    atomicAdd(&cnt, c);
    __syncthreads();
    if (threadIdx.x == 0) *flag = (cnt > 64) ? 1 : 0;
}

// ---------- generic cast-to-bf16 (or copy) ----------
__global__ void cast_bf16(const void* __restrict__ src, u16* __restrict__ dst, int n,
                          const int* __restrict__ flagp) {
    int i = blockIdx.x * 256 + threadIdx.x;
    if (i >= n) return;
    dst[i] = (*flagp) ? f2b(((const float*)src)[i]) : ((const u16*)src)[i];
}

// ---------- generic transpose with offsets, dynamic in/out dtype ----------
__global__ __launch_bounds__(256) void transpose_g(const void* __restrict__ in,
                                                   void* __restrict__ out,
                                                   int R, int Cfull, int c0, int ostride,
                                                   long ioff, long ibstride,
                                                   long ooff, long obstride,
                                                   const int* __restrict__ flagp,
                                                   int in_dyn, int out_dyn) {
    __shared__ u16 t[32][33];
    const int f = *flagp;
    const int in_f32 = in_dyn & f, out_f32 = out_dyn & f;
    const long ib = ioff + (long)blockIdx.z * ibstride;
    const long ob = ooff + (long)blockIdx.z * obstride;
    int cl0 = blockIdx.x * 32, r0 = blockIdx.y * 32;
    int tx = threadIdx.x, ty = threadIdx.y;   // block (32,8)
    const float* inf = (const float*)in;
    const u16* inh = (const u16*)in;
#pragma unroll
    for (int i = 0; i < 4; i++) {
        long src = ib + (long)(r0 + ty + i * 8) * Cfull + c0 + cl0 + tx;
        t[ty + i * 8][tx] = in_f32 ? f2b(inf[src]) : inh[src];
    }
    __syncthreads();
#pragma unroll
    for (int i = 0; i < 4; i++) {
        long dst = ob + (long)(cl0 + ty + i * 8) * ostride + r0 + tx;
        u16 v = t[tx][ty + i * 8];
        if (out_f32) ((float*)out)[dst] = b2f(v);
        else         ((u16*)out)[dst] = v;
    }
}

// ---------- repack up_w [c(512)][o(256)][kh][kw] -> WU [(khw*256+o)][c] ----------
__global__ void repack_w(const void* __restrict__ uw, u16* __restrict__ wu,
                         const int* __restrict__ flagp) {
    int o_ = blockIdx.x * 256 + threadIdx.x;      // 524288 total
    int ccol = o_ & 511, nrow = o_ >> 9;
    int o = nrow & 255, khw = nrow >> 8;
    int src = ccol * 1024 + o * 4 + khw;
    wu[o_] = (*flagp) ? f2b(((const float*)uw)[src]) : ((const u16*)uw)[src];
}

// ---------- GEMM: C[M,N] = epi(A[M,K] @ W[N,K]^T + bias + R); bf16 in/out, fp32 acc
__global__ __launch_bounds__(256) void gemm_bf16(const u16* __restrict__ A,
                                                 const u16* __restrict__ W,
                                                 const u16* __restrict__ bias,
                                                 const u16* __restrict__ Rres,
                                                 u16* __restrict__ C,
                                                 int M, int N, int K, int gelu) {
    __shared__ u16 As[128][40];
    __shared__ u16 Bs[128][40];
    const int tid = threadIdx.x;
    const int m0 = blockIdx.y * 128, n0 = blockIdx.x * 128;
    const int wave = tid >> 6, lane = tid & 63;
    const int wm = (wave >> 1) * 64, wn = (wave & 1) * 64;
    const int quad = lane >> 4, l16 = lane & 15;
    const int rA = tid >> 2, kp = (tid & 3) * 8;

    f32x4 acc[4][4];
#pragma unroll
    for (int i = 0; i < 4; i++)
#pragma unroll
        for (int j = 0; j < 4; j++)
#pragma unroll
            for (int r = 0; r < 4; r++) acc[i][j][r] = 0.f;

    for (int kt = 0; kt < K; kt += 32) {
#pragma unroll
        for (int r = 0; r < 2; r++) {
            int row = rA + r * 64;
            *(uint4*)&As[row][kp] = *(const uint4*)&A[(size_t)(m0 + row) * K + kt + kp];
            *(uint4*)&Bs[row][kp] = *(const uint4*)&W[(size_t)(n0 + row) * K + kt + kp];
        }
        __syncthreads();
        bf16x8 af[4], bfr[4];
#pragma unroll
        for (int i = 0; i < 4; i++) {
            af[i]  = *(const bf16x8*)&As[wm + i * 16 + l16][quad * 8];
            bfr[i] = *(const bf16x8*)&Bs[wn + i * 16 + l16][quad * 8];
        }
#pragma unroll
        for (int i = 0; i < 4; i++)
#pragma unroll
            for (int j = 0; j < 4; j++)
                acc[i][j] = __builtin_amdgcn_mfma_f32_16x16x32_bf16(af[i], bfr[j], acc[i][j], 0, 0, 0);
        __syncthreads();
    }

#pragma unroll
    for (int i = 0; i < 4; i++)
#pragma unroll
        for (int j = 0; j < 4; j++) {
            int col = n0 + wn + j * 16 + l16;
            float bv = bias ? b2f(bias[col]) : 0.f;
#pragma unroll
            for (int r = 0; r < 4; r++) {
                int rowg = m0 + wm + i * 16 + quad * 4 + r;
                float v = acc[i][j][r] + bv;
                if (Rres) v += b2f(Rres[(size_t)rowg * N + col]);
                if (gelu) v = 0.5f * v * (1.f + erff(v * 0.70710678118654752f));
                C[(size_t)rowg * N + col] = f2b(v);
            }
        }
}

// ---------- convT epilogue: scatter TMPC[m=(pix)][n=(khw,o)] -> SC[tok,o] + bias ----------
__global__ void conv_epilogue(const u16* __restrict__ t, const u16* __restrict__ ub,
                              u16* __restrict__ sc) {
    int idx = blockIdx.x * 256 + threadIdx.x;     // T*256 total
    int c = idx & 255, rest = idx >> 8;
    int Ww = rest & 127, Hl = rest >> 7;
    int m = (Hl >> 1) * 64 + (Ww >> 1);
    int n = (((Hl & 1) * 2 + (Ww & 1)) << 8) + c;
    sc[idx] = f2b(b2f(t[(size_t)m * 1024 + n]) + b2f(ub[c]));
}

// ---------- layernorm over C=256, optional window-partition remap ----------
__global__ __launch_bounds__(256) void ln_kernel(const u16* __restrict__ in,
                                                 const u16* __restrict__ g,
                                                 const u16* __restrict__ bta,
                                                 u16* __restrict__ out, int remap) {
    int wave = threadIdx.x >> 6, lane = threadIdx.x & 63;
    int row = blockIdx.x * 4 + wave;
    const u16* ip = in + (size_t)row * 256 + lane * 4;
    ushort4 u = *(const ushort4*)ip;
    float x0 = b2f(u.x), x1 = b2f(u.y), x2 = b2f(u.z), x3 = b2f(u.w);
    float s1 = x0 + x1 + x2 + x3;
    float s2 = x0 * x0 + x1 * x1 + x2 * x2 + x3 * x3;
#pragma unroll
    for (int o = 32; o > 0; o >>= 1) { s1 += __shfl_xor(s1, o); s2 += __shfl_xor(s2, o); }
    float mu = s1 * (1.f / 256.f);
    float var = s2 * (1.f / 256.f) - mu * mu;
    float rstd = rsqrtf(var + 1e-6f);
    int orow = row;
    if (remap) {
        int Hl = row >> 7, Ww = row & 127;
        orow = ((Hl >> 3) * 16 + (Ww >> 3)) * 64 + (Hl & 7) * 8 + (Ww & 7);
    }
    ushort4 gv = *(const ushort4*)(g + lane * 4);
    ushort4 bv = *(const ushort4*)(bta + lane * 4);
    ushort4 o;
    o.x = f2b((x0 - mu) * rstd * b2f(gv.x) + b2f(bv.x));
    o.y = f2b((x1 - mu) * rstd * b2f(gv.y) + b2f(bv.y));
    o.z = f2b((x2 - mu) * rstd * b2f(gv.z) + b2f(bv.z));
    o.w = f2b((x3 - mu) * rstd * b2f(gv.w) + b2f(bv.w));
    *(ushort4*)(out + (size_t)orow * 256 + lane * 4) = o;
}

// ---------- MFMA attention: one wave per (window, head); N=64 tokens, hd=32 ----------
// S = Q@K^T (16 mfma) -> scale+bias -> softmax in-register -> P via LDS -> O = P@V (16 mfma)
__global__ __launch_bounds__(64) void attn_mfma(const u16* __restrict__ qkv,
                                                const u16* __restrict__ tbl,
                                                u16* __restrict__ out) {
    __shared__ u16 P[64][72];   // 144B row stride: 16B-aligned for ds_read_b128
    const int wh = blockIdx.x;
    const int w = wh >> 3, h = wh & 7;
    const int lane = threadIdx.x;
    const int l16 = lane & 15, quad = lane >> 4;
    const u16* base = qkv + (size_t)w * 64 * 768 + h * 32;

    // Q,K fragments: A/B[m][k] with m=l16(+tile), k=quad*8+j (contiguous 16B)
    bf16x8 qf[4], kf[4];
#pragma unroll
    for (int t = 0; t < 4; t++) {
        qf[t] = *(const bf16x8*)(base + (size_t)(t * 16 + l16) * 768 + quad * 8);
        kf[t] = *(const bf16x8*)(base + (size_t)(t * 16 + l16) * 768 + 256 + quad * 8);
    }
    f32x4 s[4][4];
#pragma unroll
    for (int mi = 0; mi < 4; mi++)
#pragma unroll
        for (int nj = 0; nj < 4; nj++) {
            f32x4 z = {0.f, 0.f, 0.f, 0.f};
            s[mi][nj] = __builtin_amdgcn_mfma_f32_16x16x32_bf16(qf[mi], kf[nj], z, 0, 0, 0);
        }

    // softmax per row i = mi*16 + quad*4 + r  (C layout: row=quad*4+r, col=l16)
    const float scale = 0.17677669529663687f;   // 32^-0.5
    float inv[4][4];
#pragma unroll
    for (int mi = 0; mi < 4; mi++) {
#pragma unroll
        for (int r = 0; r < 4; r++) {
            int i = mi * 16 + quad * 4 + r;
            int yi = i >> 3, xi = i & 7;
            float v[4];
            float mx = -1e30f;
#pragma unroll
            for (int nj = 0; nj < 4; nj++) {
                int j = nj * 16 + l16;
                int dy = yi - (j >> 3) + 7, dx = xi - (j & 7) + 7;
                v[nj] = s[mi][nj][r] * scale + b2f(tbl[(dy * 15 + dx) * 8 + h]);
                mx = fmaxf(mx, v[nj]);
            }
#pragma unroll
            for (int o = 8; o > 0; o >>= 1) mx = fmaxf(mx, __shfl_xor(mx, o));
            float sum = 0.f;
#pragma unroll
            for (int nj = 0; nj < 4; nj++) { v[nj] = __expf(v[nj] - mx); sum += v[nj]; }
#pragma unroll
            for (int o = 8; o > 0; o >>= 1) sum += __shfl_xor(sum, o);
            inv[mi][r] = 1.f / sum;
#pragma unroll
            for (int nj = 0; nj < 4; nj++) P[i][nj * 16 + l16] = f2b(v[nj]);
        }
    }
    __syncthreads();

    // O = P @ V : A-frag from LDS (b128), B-frag = V^T gathered from global
    f32x4 o[4][2];
#pragma unroll
    for (int mi = 0; mi < 4; mi++)
#pragma unroll
        for (int nj = 0; nj < 2; nj++)
#pragma unroll
            for (int r = 0; r < 4; r++) o[mi][nj][r] = 0.f;
#pragma unroll
    for (int ks = 0; ks < 2; ks++) {
        bf16x8 vf[2];
#pragma unroll
        for (int nj = 0; nj < 2; nj++) {
            u16 tmp[8];
#pragma unroll
            for (int j = 0; j < 8; j++)
                tmp[j] = base[(size_t)(ks * 32 + quad * 8 + j) * 768 + 512 + nj * 16 + l16];
            vf[nj] = *(bf16x8*)tmp;
        }
#pragma unroll
        for (int mi = 0; mi < 4; mi++) {
            bf16x8 pf = *(const bf16x8*)&P[mi * 16 + l16][ks * 32 + quad * 8];
#pragma unroll
            for (int nj = 0; nj < 2; nj++)
                o[mi][nj] = __builtin_amdgcn_mfma_f32_16x16x32_bf16(pf, vf[nj], o[mi][nj], 0, 0, 0);
        }
    }
    u16* ob = out + (size_t)w * 64 * 256 + h * 32;
#pragma unroll
    for (int mi = 0; mi < 4; mi++)
#pragma unroll
        for (int nj = 0; nj < 2; nj++)
#pragma unroll
            for (int r = 0; r < 4; r++) {
                int m = mi * 16 + quad * 4 + r;
                ob[(size_t)m * 256 + nj * 16 + l16] = f2b(o[mi][nj][r] * inv[mi][r]);
            }
}

// ---------- window reverse + shortcut add ----------
__global__ void rev_add(const u16* __restrict__ sc, const u16* __restrict__ t2,
                        u16* __restrict__ xr) {
    int idx = blockIdx.x * 256 + threadIdx.x;
    int c = idx & 255, rest = idx >> 8;
    int Ww = rest & 127, Hl = rest >> 7;
    int wr = ((Hl >> 3) * 16 + (Ww >> 3)) * 64 + (Hl & 7) * 8 + (Ww & 7);
    xr[idx] = f2b(b2f(sc[idx]) + b2f(t2[(size_t)wr * 256 + c]));
}

// =====================================================================
extern "C" void kernel_launch(void* const* d_in, const int* in_sizes, int n_in,
                              void* d_out, int out_size, void* d_ws, size_t ws_size,
                              hipStream_t stream) {
    const void* x      = d_in[0];
    const void* skip   = d_in[1];
    const void* up_w   = d_in[2];

    u16* ws = (u16*)d_ws;
    int* flag = (int*)ws;
    u16* WU  = ws + 32;
    size_t off = 32 + 524288;
    u16* SW  = ws + off; off += 65536;
    u16* QW  = ws + off; off += 196608;
    u16* PW  = ws + off; off += 65536;
    u16* W1  = ws + off; off += 262144;
    u16* W2  = ws + off; off += 262144;
    u16* UB  = ws + off; off += 256;
    u16* QB  = ws + off; off += 768;
    u16* PB  = ws + off; off += 256;
    u16* B1  = ws + off; off += 1024;
    u16* B2  = ws + off; off += 256;
    u16* G1  = ws + off; off += 256;
    u16* Bn1 = ws + off; off += 256;
    u16* G2  = ws + off; off += 256;
    u16* Bn2 = ws + off; off += 256;
    u16* TBL = ws + off; off += 1808;
    off = (off + 63) & ~(size_t)63;
    u16* AR = ws + off;

    long arena = (long)(ws_size / 2) - (long)off;
    int T = 1024;
    const int cand[8] = {131072, 65536, 32768, 16384, 8192, 4096, 2048, 1024};
    for (int i = 0; i < 8; i++)
        if ((long)cand[i] * 2048 <= arena) { T = cand[i]; break; }

    u16* SLA = AR;
    u16* XT  = SLA;
    u16* TMPC = SLA + (size_t)T * 128;
    u16* SLB = AR + (size_t)T * 1024;
    u16* SLC = AR + (size_t)T * 1280;
    u16* SC  = AR + (size_t)T * 1536;
    u16* XR  = AR + (size_t)T * 1792;

    detect_dtype<<<1, 256, 0, stream>>>((const u16*)x, flag);
    cast_bf16<<<256, 256, 0, stream>>>(d_in[4],  SW, 65536, flag);
    cast_bf16<<<768, 256, 0, stream>>>(d_in[9],  QW, 196608, flag);
    cast_bf16<<<256, 256, 0, stream>>>(d_in[11], PW, 65536, flag);
    cast_bf16<<<1024, 256, 0, stream>>>(d_in[14], W1, 262144, flag);
    cast_bf16<<<1024, 256, 0, stream>>>(d_in[16], W2, 262144, flag);
    cast_bf16<<<1, 256, 0, stream>>>(d_in[3],  UB, 256, flag);
    cast_bf16<<<3, 256, 0, stream>>>(d_in[10], QB, 768, flag);
    cast_bf16<<<1, 256, 0, stream>>>(d_in[12], PB, 256, flag);
    cast_bf16<<<4, 256, 0, stream>>>(d_in[15], B1, 1024, flag);
    cast_bf16<<<1, 256, 0, stream>>>(d_in[17], B2, 256, flag);
    cast_bf16<<<1, 256, 0, stream>>>(d_in[5],  G1, 256, flag);
    cast_bf16<<<1, 256, 0, stream>>>(d_in[6],  Bn1, 256, flag);
    cast_bf16<<<1, 256, 0, stream>>>(d_in[7],  G2, 256, flag);
    cast_bf16<<<1, 256, 0, stream>>>(d_in[8],  Bn2, 256, flag);
    cast_bf16<<<8, 256, 0, stream>>>(d_in[13], TBL, 1800, flag);
    repack_w<<<2048, 256, 0, stream>>>(up_w, WU, flag);

    dim3 tb(32, 8);
    const int nb = T / 16384;
    const int Hs = T / 128;
    const int nchunks = (nb >= 1) ? (8 / nb) : (8 * (128 / Hs));

    for (int c = 0; c < nchunks; c++) {
        int b, h0, z;
        if (nb >= 1) { b = c * nb; h0 = 0; z = nb; }
        else { b = c / (128 / Hs); h0 = (c % (128 / Hs)) * Hs; z = 1; }

        transpose_g<<<dim3((nb >= 1) ? 128 : Hs, 16, z), tb, 0, stream>>>(
            x, XT, 512, 4096, (nb >= 1) ? 0 : h0 * 32, 512,
            (long)b * 2097152, 2097152, 0, 2097152, flag, 1, 0);
        gemm_bf16<<<dim3(8, T / 512), 256, 0, stream>>>(XT, WU, nullptr, nullptr, TMPC,
                                                        T / 4, 1024, 512, 0);
        conv_epilogue<<<T, 256, 0, stream>>>(TMPC, UB, SC);
        transpose_g<<<dim3((nb >= 1) ? 512 : Hs * 4, 8, z), tb, 0, stream>>>(
            skip, SLB, 256, 16384, (nb >= 1) ? 0 : h0 * 128, 256,
            (long)b * 4194304, 4194304, 0, 4194304, flag, 1, 0);
        gemm_bf16<<<dim3(2, T / 128), 256, 0, stream>>>(SLB, SW, nullptr, SC, SLC, T, 256, 256, 0);
        ln_kernel<<<T / 4, 256, 0, stream>>>(SLC, G1, Bn1, SLB, 1);
        gemm_bf16<<<dim3(6, T / 128), 256, 0, stream>>>(SLB, QW, QB, nullptr, SLA, T, 768, 256, 0);
        attn_mfma<<<T / 8, 64, 0, stream>>>(SLA, TBL, SLC);
        gemm_bf16<<<dim3(2, T / 128), 256, 0, stream>>>(SLC, PW, PB, nullptr, SLB, T, 256, 256, 0);
        rev_add<<<T, 256, 0, stream>>>(SC, SLB, XR);
        ln_kernel<<<T / 4, 256, 0, stream>>>(XR, G2, Bn2, SLC, 0);
        gemm_bf16<<<dim3(8, T / 128), 256, 0, stream>>>(SLC, W1, B1, nullptr, SLA, T, 1024, 256, 1);
        gemm_bf16<<<dim3(2, T / 128), 256, 0, stream>>>(SLA, W2, B2, XR, SLB, T, 256, 1024, 0);
        if (nb >= 1)
            transpose_g<<<dim3(8, 512, z), tb, 0, stream>>>(
                SLB, d_out, 16384, 256, 0, 16384,
                0, 4194304, (long)b * 4194304, 4194304, flag, 0, 1);
        else
            transpose_g<<<dim3(8, T / 32, 1), tb, 0, stream>>>(
                SLB, d_out, T, 256, 0, 16384,
                0, 0, (long)b * 4194304 + h0 * 128, 0, flag, 0, 1);
    }
}